// Round 5
// baseline (723.260 us; speedup 1.0000x reference)
//
#include <hip/hip_runtime.h>
#include <hip/hip_bf16.h>
#include <stdint.h>

#define NN 50000
#define NE 800000
#define EPS 1e-5f

// CSR bucket params
#define KB 196       // buckets = ceil(NN / NPB)
#define SH 8         // bucket = dst >> SH
#define NPB 256      // nodes per bucket
#define RCAP 4500    // slots per bucket (mean 4082, +6.6 sigma)
#define PTP 512      // edges per payload-partition block
#define PT2 2048     // edges per DS-partition block

typedef __attribute__((ext_vector_type(8))) short bf16x8;
typedef __attribute__((ext_vector_type(4))) float floatx4;

static __device__ __forceinline__ float bf2f(unsigned int u){
  union { unsigned int i; float f; } c; c.i = u << 16; return c.f;
}
static __device__ __forceinline__ unsigned short f2bf(float f){
  union { float f; unsigned int i; } c; c.f = f;
  unsigned int x = c.i;
  return (unsigned short)((x + 0x7fffu + ((x >> 16) & 1u)) >> 16);
}

// fused f32 -> bf16 converter for x + the 6 GEMM weight matrices; also zeros bucket cursors
#define CVT_X   3200000
#define CVT_W1  3212288
#define CVT_WL2 3228672
#define CVT_WR2 3245056
#define CVT_WL3 3261440
#define CVT_WR3 3277824
#define CVT_END 3290112
__global__ void k_cvt_all(const float* __restrict__ x,  const float* __restrict__ W1,
                          const float* __restrict__ Wl2, const float* __restrict__ Wr2,
                          const float* __restrict__ Wl3, const float* __restrict__ Wr3,
                          const float* __restrict__ W4,
                          unsigned short* __restrict__ xb,  unsigned short* __restrict__ W1b,
                          unsigned short* __restrict__ Wl2b, unsigned short* __restrict__ Wr2b,
                          unsigned short* __restrict__ Wl3b, unsigned short* __restrict__ Wr3b,
                          unsigned short* __restrict__ W4b, int* __restrict__ gcur){
  int i = blockIdx.x * 256 + threadIdx.x;
  if(i >= CVT_END) return;
  if(i < 3 * KB) gcur[i] = 0;
  if(i < CVT_X)        xb[i] = f2bf(x[i]);
  else if(i < CVT_W1)  W1b[i - CVT_X]    = f2bf(W1[i - CVT_X]);
  else if(i < CVT_WL2) Wl2b[i - CVT_W1]  = f2bf(Wl2[i - CVT_W1]);
  else if(i < CVT_WR2) Wr2b[i - CVT_WL2] = f2bf(Wr2[i - CVT_WL2]);
  else if(i < CVT_WL3) Wl3b[i - CVT_WR2] = f2bf(Wl3[i - CVT_WR2]);
  else if(i < CVT_WR3) Wr3b[i - CVT_WL3] = f2bf(Wr3[i - CVT_WL3]);
  else                 W4b[i - CVT_WR3]  = f2bf(W4[i - CVT_WR3]);
}

// ---- layer-0 partition WITH ea payload: streams ei + ea sequentially,
// writes bucket-grouped recDS {dst,src} and recEA (32 bf16 = 64B rows) ----
__global__ void k_partP(const int* __restrict__ ei, const float* __restrict__ ea,
                        int* __restrict__ gcur,
                        int2* __restrict__ recDS, unsigned int* __restrict__ recEA){
  __shared__ int2 stage[PTP];
  __shared__ int slotArr[PTP];
  __shared__ unsigned int pay[PTP * 16];
  __shared__ int hist[KB], ex[KB], cur[KB], gbase[KB];
  __shared__ int tot;
  int tid = threadIdx.x;
  int tile = blockIdx.x * PTP;
  int cnt_local = NE - tile; if(cnt_local > PTP) cnt_local = PTP;
  for(int i = tid; i < KB; i += 256) hist[i] = 0;
  __syncthreads();
  int dst[2], src[2];
  #pragma unroll
  for(int j = 0; j < 2; j++){
    int t = j * 256 + tid;
    if(t < cnt_local){ src[j] = ei[tile + t]; dst[j] = ei[NE + tile + t]; atomicAdd(&hist[dst[j] >> SH], 1); }
    else dst[j] = -1;
  }
  __syncthreads();
  if(tid == 0){ int run = 0; for(int b = 0; b < KB; b++){ ex[b] = run; cur[b] = run; run += hist[b]; } tot = run; }
  if(tid < KB) gbase[tid] = atomicAdd(&gcur[tid], hist[tid]);
  __syncthreads();
  #pragma unroll
  for(int j = 0; j < 2; j++){
    if(dst[j] >= 0){
      int b = dst[j] >> SH;
      int s = atomicAdd(&cur[b], 1);
      stage[s] = make_int2(dst[j], src[j]);
      slotArr[j * 256 + tid] = s;
    }
  }
  __syncthreads();
  // payload: sequential coalesced ea read, scatter into LDS by slot (16 lanes per edge)
  {
    int g = tid >> 4, li = tid & 15;
    for(int t = g; t < cnt_local; t += 16){
      int s = slotArr[t];
      float2 v = *(const float2*)(ea + (size_t)(tile + t) * 32 + li * 2);
      pay[s * 16 + li] = (unsigned int)f2bf(v.x) | ((unsigned int)f2bf(v.y) << 16);
    }
  }
  __syncthreads();
  // flush DS recs (bucket-run grouped)
  for(int s = tid; s < tot; s += 256){
    int2 r = stage[s];
    int b = r.x >> SH;
    recDS[b * RCAP + gbase[b] + (s - ex[b])] = r;
  }
  // flush payload rows (4 lanes x 16B per row, rows in s-order => bucket-run contiguous)
  {
    int g4 = tid >> 2, l4 = tid & 3;
    for(int s = g4; s < tot; s += 64){
      int b = stage[s].x >> SH;
      int dslot = b * RCAP + gbase[b] + (s - ex[b]);
      uint4 v = *(uint4*)&pay[s * 16 + l4 * 4];
      *((uint4*)(recEA + (size_t)dslot * 16) + l4) = v;
    }
  }
}

// ---- DS-only partition for layers 1/2 ----
__global__ void k_part(const int* __restrict__ ei, int* __restrict__ gcur, int2* __restrict__ rec){
  __shared__ int2 stage[PT2];
  __shared__ int hist[KB], ex[KB], cur[KB], gbase[KB];
  __shared__ int tot;
  int tid = threadIdx.x;
  int tile = blockIdx.x * PT2;
  for(int i = tid; i < KB; i += 256) hist[i] = 0;
  __syncthreads();
  int dst[8], src[8];
  #pragma unroll
  for(int j = 0; j < 8; j++){
    int e = tile + j * 256 + tid;
    if(e < NE){ src[j] = ei[e]; dst[j] = ei[NE + e]; atomicAdd(&hist[dst[j] >> SH], 1); }
    else dst[j] = -1;
  }
  __syncthreads();
  if(tid == 0){ int run = 0; for(int b = 0; b < KB; b++){ ex[b] = run; cur[b] = run; run += hist[b]; } tot = run; }
  if(tid < KB) gbase[tid] = atomicAdd(&gcur[tid], hist[tid]);
  __syncthreads();
  #pragma unroll
  for(int j = 0; j < 8; j++){
    if(dst[j] >= 0){
      int b = dst[j] >> SH;
      int s = atomicAdd(&cur[b], 1);
      stage[s] = make_int2(dst[j], src[j]);
    }
  }
  __syncthreads();
  for(int s = tid; s < tot; s += 256){
    int2 r = stage[s];
    int b = r.x >> SH;
    rec[b * RCAP + gbase[b] + (s - ex[b])] = r;
  }
}

// ---- per-bucket CSR build: one block per bucket (256 nodes, thread per node) ----
__global__ void k_build(const int2* __restrict__ rec, const int* __restrict__ gcnt,
                        int* __restrict__ adj, int* __restrict__ rowbeg, int* __restrict__ deg){
  __shared__ int cnt[NPB], ex2[NPB], cur2[NPB];
  __shared__ int part[256];
  int b = blockIdx.x, tid = threadIdx.x;
  int n0 = b << SH;
  int nr = gcnt[b];
  const int2* r = rec + b * RCAP;
  cnt[tid] = 0;
  __syncthreads();
  for(int k = tid; k < nr; k += 256) atomicAdd(&cnt[r[k].x - n0], 1);
  __syncthreads();
  int c0 = cnt[tid];
  part[tid] = c0;
  __syncthreads();
  for(int d = 1; d < 256; d <<= 1){
    int v = (tid >= d) ? part[tid - d] : 0;
    __syncthreads();
    part[tid] += v;
    __syncthreads();
  }
  int base = part[tid] - c0;
  ex2[tid] = base; cur2[tid] = base;
  __syncthreads();
  int n = n0 + tid;
  if(n < NN){ rowbeg[n] = b * RCAP + base; deg[n] = c0; }
  for(int k = tid; k < nr; k += 256){
    int2 q = r[k];
    int p = atomicAdd(&cur2[q.x - n0], 1);
    adj[b * RCAP + p] = q.y;
  }
}

// ---- bucket ea aggregation: stream payload sequentially, LDS f32 accumulate ----
__global__ void k_aggEA(const int2* __restrict__ recDS, const unsigned int* __restrict__ recEA,
                        const int* __restrict__ gcnt, unsigned short* __restrict__ agg){
  __shared__ float accf[NPB][33];   // pad to 33 to break bank aliasing
  __shared__ int cnt[NPB];
  int b = blockIdx.x, tid = threadIdx.x;
  int n0 = b << SH;
  int nr = gcnt[b];
  for(int i = tid; i < NPB * 33; i += 256) ((float*)accf)[i] = 0.f;
  cnt[tid] = 0;
  __syncthreads();
  int g = tid >> 4, li = tid & 15;
  for(int s = g; s < nr; s += 16){
    int2 r = recDS[b * RCAP + s];
    int row = r.x - n0;
    unsigned int p = recEA[(size_t)(b * RCAP + s) * 16 + li];
    atomicAdd(&accf[row][li * 2],     bf2f(p & 0xffffu));
    atomicAdd(&accf[row][li * 2 + 1], bf2f(p >> 16));
    if(li == 0) atomicAdd(&cnt[row], 1);
  }
  __syncthreads();
  int n = n0 + tid;
  if(n < NN){
    int c = cnt[tid];
    float inv = 1.0f / (float)(c > 0 ? c : 1);
    unsigned int pk[16];
    #pragma unroll
    for(int d = 0; d < 16; d++)
      pk[d] = (unsigned int)f2bf(accf[tid][2 * d] * inv) | ((unsigned int)f2bf(accf[tid][2 * d + 1] * inv) << 16);
    uint4* dst4 = (uint4*)(agg + (size_t)n * 96 + 64);
    #pragma unroll
    for(int q = 0; q < 4; q++)
      dst4[q] = make_uint4(pk[4 * q], pk[4 * q + 1], pk[4 * q + 2], pk[4 * q + 3]);
  }
}

// ---- x-side aggregation: wave per node; 8 lanes/edge x 8 edges/iter x 2 unroll ----
__global__ void k_aggX(const int* __restrict__ rowbeg, const int* __restrict__ deg,
                       const int* __restrict__ adj,
                       const unsigned short* __restrict__ xb, unsigned short* __restrict__ agg){
  int w = (blockIdx.x * blockDim.x + threadIdx.x) >> 6;
  int lane = threadIdx.x & 63;
  if(w >= NN) return;
  int sub = lane >> 3, li = lane & 7;
  int r0 = rowbeg[w], dg = deg[w], r1 = r0 + dg;
  float acc[8] = {0.f,0.f,0.f,0.f,0.f,0.f,0.f,0.f};
  for(int k = r0; k < r1; k += 16){
    int e0 = k + sub, e1 = k + 8 + sub;
    int i0 = e0 < r1 ? e0 : r1 - 1;
    int i1 = e1 < r1 ? e1 : r1 - 1;
    float m0 = e0 < r1 ? 1.f : 0.f;
    float m1 = e1 < r1 ? 1.f : 0.f;
    int s0 = adj[i0], s1 = adj[i1];
    uint4 v0 = *(const uint4*)(xb + s0 * 64 + li * 8);
    uint4 v1 = *(const uint4*)(xb + s1 * 64 + li * 8);
    acc[0] += m0 * bf2f(v0.x & 0xffffu); acc[1] += m0 * bf2f(v0.x >> 16);
    acc[2] += m0 * bf2f(v0.y & 0xffffu); acc[3] += m0 * bf2f(v0.y >> 16);
    acc[4] += m0 * bf2f(v0.z & 0xffffu); acc[5] += m0 * bf2f(v0.z >> 16);
    acc[6] += m0 * bf2f(v0.w & 0xffffu); acc[7] += m0 * bf2f(v0.w >> 16);
    acc[0] += m1 * bf2f(v1.x & 0xffffu); acc[1] += m1 * bf2f(v1.x >> 16);
    acc[2] += m1 * bf2f(v1.y & 0xffffu); acc[3] += m1 * bf2f(v1.y >> 16);
    acc[4] += m1 * bf2f(v1.z & 0xffffu); acc[5] += m1 * bf2f(v1.z >> 16);
    acc[6] += m1 * bf2f(v1.w & 0xffffu); acc[7] += m1 * bf2f(v1.w >> 16);
  }
  #pragma unroll
  for(int d = 8; d < 64; d <<= 1){
    #pragma unroll
    for(int i = 0; i < 8; i++) acc[i] += __shfl_xor(acc[i], d, 64);
  }
  if(sub == 0){
    float inv = 1.0f / (float)(dg > 0 ? dg : 1);
    unsigned int p0 = (unsigned int)f2bf(acc[0]*inv) | ((unsigned int)f2bf(acc[1]*inv) << 16);
    unsigned int p1 = (unsigned int)f2bf(acc[2]*inv) | ((unsigned int)f2bf(acc[3]*inv) << 16);
    unsigned int p2 = (unsigned int)f2bf(acc[4]*inv) | ((unsigned int)f2bf(acc[5]*inv) << 16);
    unsigned int p3 = (unsigned int)f2bf(acc[6]*inv) | ((unsigned int)f2bf(acc[7]*inv) << 16);
    *(uint4*)(agg + (size_t)w * 96 + li * 8) = make_uint4(p0, p1, p2, p3);
  }
}

// ---- h aggregation: wave per node; 16 lanes/edge x 4 edges/iter x 2 unroll ----
__global__ void k_aggH(const int* __restrict__ rowbeg, const int* __restrict__ deg,
                       const int* __restrict__ adj,
                       const unsigned short* __restrict__ h, unsigned short* __restrict__ agg){
  int w = (blockIdx.x * blockDim.x + threadIdx.x) >> 6;
  int lane = threadIdx.x & 63;
  if(w >= NN) return;
  int sub = lane >> 4, li = lane & 15;
  int r0 = rowbeg[w], dg = deg[w], r1 = r0 + dg;
  float acc[8] = {0.f,0.f,0.f,0.f,0.f,0.f,0.f,0.f};
  for(int k = r0; k < r1; k += 8){
    int e0 = k + sub, e1 = k + 4 + sub;
    int i0 = e0 < r1 ? e0 : r1 - 1;
    int i1 = e1 < r1 ? e1 : r1 - 1;
    float m0 = e0 < r1 ? 1.f : 0.f;
    float m1 = e1 < r1 ? 1.f : 0.f;
    int s0 = adj[i0], s1 = adj[i1];
    uint4 v0 = *(const uint4*)(h + s0 * 128 + li * 8);
    uint4 v1 = *(const uint4*)(h + s1 * 128 + li * 8);
    acc[0] += m0 * bf2f(v0.x & 0xffffu); acc[1] += m0 * bf2f(v0.x >> 16);
    acc[2] += m0 * bf2f(v0.y & 0xffffu); acc[3] += m0 * bf2f(v0.y >> 16);
    acc[4] += m0 * bf2f(v0.z & 0xffffu); acc[5] += m0 * bf2f(v0.z >> 16);
    acc[6] += m0 * bf2f(v0.w & 0xffffu); acc[7] += m0 * bf2f(v0.w >> 16);
    acc[0] += m1 * bf2f(v1.x & 0xffffu); acc[1] += m1 * bf2f(v1.x >> 16);
    acc[2] += m1 * bf2f(v1.y & 0xffffu); acc[3] += m1 * bf2f(v1.y >> 16);
    acc[4] += m1 * bf2f(v1.z & 0xffffu); acc[5] += m1 * bf2f(v1.z >> 16);
    acc[6] += m1 * bf2f(v1.w & 0xffffu); acc[7] += m1 * bf2f(v1.w >> 16);
  }
  #pragma unroll
  for(int d = 16; d < 64; d <<= 1){
    #pragma unroll
    for(int i = 0; i < 8; i++) acc[i] += __shfl_xor(acc[i], d, 64);
  }
  if(sub == 0){
    float inv = 1.0f / (float)(dg > 0 ? dg : 1);
    unsigned int p0 = (unsigned int)f2bf(acc[0]*inv) | ((unsigned int)f2bf(acc[1]*inv) << 16);
    unsigned int p1 = (unsigned int)f2bf(acc[2]*inv) | ((unsigned int)f2bf(acc[3]*inv) << 16);
    unsigned int p2 = (unsigned int)f2bf(acc[4]*inv) | ((unsigned int)f2bf(acc[5]*inv) << 16);
    unsigned int p3 = (unsigned int)f2bf(acc[6]*inv) | ((unsigned int)f2bf(acc[7]*inv) << 16);
    *(uint4*)(agg + (size_t)w * 128 + li * 8) = make_uint4(p0, p1, p2, p3);
  }
}

// conv1 dense part: h1 = relu(bn(relu(mask_deg(agg @ W1^T + b1))))
__global__ void k_lin1(const unsigned short* __restrict__ agg, const unsigned short* __restrict__ W1,
                       const float* __restrict__ b1,
                       const float* __restrict__ g1, const float* __restrict__ be1,
                       const float* __restrict__ m1, const float* __restrict__ v1,
                       const int* __restrict__ deg, unsigned short* __restrict__ h1){
  int wave = (blockIdx.x * blockDim.x + threadIdx.x) >> 6;
  int lane = threadIdx.x & 63;
  int mt = wave >> 3, nt = wave & 7;
  if(mt >= 3125) return;
  int node0 = mt * 16;
  int col = lane & 15, quad = lane >> 4;
  int o = nt * 16 + col;
  int arow = node0 + col;
  floatx4 acc = {0.f, 0.f, 0.f, 0.f};
  #pragma unroll
  for(int kc = 0; kc < 3; kc++){
    bf16x8 a = *(const bf16x8*)(agg + arow * 96 + kc * 32 + quad * 8);
    bf16x8 b = *(const bf16x8*)(W1 + o * 96 + kc * 32 + quad * 8);
    acc = __builtin_amdgcn_mfma_f32_16x16x32_bf16(a, b, acc, 0, 0, 0);
  }
  float bb = b1[o];
  float sc = g1[o] * rsqrtf(v1[o] + EPS);
  float mv = m1[o], bev = be1[o];
  #pragma unroll
  for(int r = 0; r < 4; r++){
    int node = node0 + quad * 4 + r;
    float pre = (deg[node] > 0) ? (acc[r] + bb) : 0.0f;   // ref: empty segment -> mean 0, bias never added
    float t = fmaxf(pre, 0.f);
    float bn = sc * (t - mv) + bev;
    h1[node * 128 + o] = f2bf(fmaxf(bn, 0.f));
  }
}

// SAGE: hout = relu(bn(agg @ Wl^T + bl + hin @ Wr^T))
__global__ void k_sage(const unsigned short* __restrict__ agg, const unsigned short* __restrict__ hin,
                       const unsigned short* __restrict__ Wl, const float* __restrict__ bl,
                       const unsigned short* __restrict__ Wr,
                       const float* __restrict__ g, const float* __restrict__ be,
                       const float* __restrict__ m, const float* __restrict__ v,
                       unsigned short* __restrict__ hout){
  int wave = (blockIdx.x * blockDim.x + threadIdx.x) >> 6;
  int lane = threadIdx.x & 63;
  int mt = wave >> 3, nt = wave & 7;
  if(mt >= 3125) return;
  int node0 = mt * 16;
  int col = lane & 15, quad = lane >> 4;
  int o = nt * 16 + col;
  int arow = node0 + col;
  floatx4 acc = {0.f, 0.f, 0.f, 0.f};
  #pragma unroll
  for(int kc = 0; kc < 4; kc++){
    bf16x8 a = *(const bf16x8*)(agg + arow * 128 + kc * 32 + quad * 8);
    bf16x8 b = *(const bf16x8*)(Wl + o * 128 + kc * 32 + quad * 8);
    acc = __builtin_amdgcn_mfma_f32_16x16x32_bf16(a, b, acc, 0, 0, 0);
  }
  #pragma unroll
  for(int kc = 0; kc < 4; kc++){
    bf16x8 a = *(const bf16x8*)(hin + arow * 128 + kc * 32 + quad * 8);
    bf16x8 b = *(const bf16x8*)(Wr + o * 128 + kc * 32 + quad * 8);
    acc = __builtin_amdgcn_mfma_f32_16x16x32_bf16(a, b, acc, 0, 0, 0);
  }
  float blv = bl[o];
  float sc = g[o] * rsqrtf(v[o] + EPS);
  float mv = m[o], bev = be[o];
  #pragma unroll
  for(int r = 0; r < 4; r++){
    int node = node0 + quad * 4 + r;
    float pre = acc[r] + blv;
    float bn = sc * (pre - mv) + bev;
    hout[node * 128 + o] = f2bf(fmaxf(bn, 0.f));
  }
}

// readout: z = relu([h3 | x] @ W4^T + b4) (64), out = z @ W5^T + b5  (f32 out)
__global__ void k_readout(const unsigned short* __restrict__ h3, const unsigned short* __restrict__ xb,
                          const unsigned short* __restrict__ W4, const float* __restrict__ b4,
                          const float* __restrict__ W5, const float* __restrict__ b5,
                          float* __restrict__ out){
  int wave = (blockIdx.x * blockDim.x + threadIdx.x) >> 6;
  int lane = threadIdx.x & 63;
  if(wave >= 3125) return;
  int node0 = wave * 16;
  int col = lane & 15, quad = lane >> 4;
  int arow = node0 + col;
  float partial[4] = {0.f, 0.f, 0.f, 0.f};
  #pragma unroll
  for(int nt = 0; nt < 4; nt++){
    int o = nt * 16 + col;
    floatx4 acc = {0.f, 0.f, 0.f, 0.f};
    #pragma unroll
    for(int kc = 0; kc < 4; kc++){
      bf16x8 a = *(const bf16x8*)(h3 + arow * 128 + kc * 32 + quad * 8);
      bf16x8 b = *(const bf16x8*)(W4 + o * 192 + kc * 32 + quad * 8);
      acc = __builtin_amdgcn_mfma_f32_16x16x32_bf16(a, b, acc, 0, 0, 0);
    }
    #pragma unroll
    for(int kc = 0; kc < 2; kc++){
      bf16x8 a = *(const bf16x8*)(xb + arow * 64 + kc * 32 + quad * 8);
      bf16x8 b = *(const bf16x8*)(W4 + o * 192 + 128 + kc * 32 + quad * 8);
      acc = __builtin_amdgcn_mfma_f32_16x16x32_bf16(a, b, acc, 0, 0, 0);
    }
    float bb = b4[o];
    float w5 = W5[o];
    #pragma unroll
    for(int r = 0; r < 4; r++)
      partial[r] += fmaxf(acc[r] + bb, 0.f) * w5;
  }
  #pragma unroll
  for(int d = 1; d < 16; d <<= 1){
    #pragma unroll
    for(int r = 0; r < 4; r++)
      partial[r] += __shfl_xor(partial[r], d, 64);
  }
  if(col == 0){
    float b5f = b5[0];
    #pragma unroll
    for(int r = 0; r < 4; r++)
      out[node0 + quad * 4 + r] = partial[r] + b5f;
  }
}

extern "C" void kernel_launch(void* const* d_in, const int* in_sizes, int n_in,
                              void* d_out, int out_size, void* d_ws, size_t ws_size,
                              hipStream_t stream) {
  const float* x   = (const float*)d_in[0];
  const int* ei0   = (const int*)d_in[1];
  const int* ei1   = (const int*)d_in[2];
  const int* ei2   = (const int*)d_in[3];
  const float* ea  = (const float*)d_in[4];
  const float* W1  = (const float*)d_in[5];
  const float* b1  = (const float*)d_in[6];
  const float* g1  = (const float*)d_in[7];
  const float* be1 = (const float*)d_in[8];
  const float* m1  = (const float*)d_in[9];
  const float* v1  = (const float*)d_in[10];
  const float* Wl2 = (const float*)d_in[11];
  const float* bl2 = (const float*)d_in[12];
  const float* Wr2 = (const float*)d_in[13];
  const float* g2  = (const float*)d_in[14];
  const float* be2 = (const float*)d_in[15];
  const float* m2  = (const float*)d_in[16];
  const float* v2  = (const float*)d_in[17];
  const float* Wl3 = (const float*)d_in[18];
  const float* bl3 = (const float*)d_in[19];
  const float* Wr3 = (const float*)d_in[20];
  const float* g3  = (const float*)d_in[21];
  const float* be3 = (const float*)d_in[22];
  const float* m3  = (const float*)d_in[23];
  const float* v3  = (const float*)d_in[24];
  const float* W4  = (const float*)d_in[25];
  const float* b4  = (const float*)d_in[26];
  const float* W5  = (const float*)d_in[27];
  const float* b5  = (const float*)d_in[28];

  char* ws = (char*)d_ws;
  size_t off = 0;
  auto alloc = [&](size_t bytes) -> void* {
    void* p = (void*)(ws + off);
    off += (bytes + 255) & ~(size_t)255;
    return p;
  };
  int* gcur    = (int*)alloc(3 * KB * sizeof(int));
  int* rowbeg3 = (int*)alloc(3 * NN * sizeof(int));
  int* deg3    = (int*)alloc(3 * NN * sizeof(int));
  int2* recDS  = (int2*)alloc((size_t)KB * RCAP * 8);     // also rec2 for L1/L2
  int* adjI    = (int*)alloc((size_t)KB * RCAP * 4);      // reused per layer
  unsigned int* recEA = (unsigned int*)alloc((size_t)KB * RCAP * 64);  // BIG: h1/aggH/h2/h3 alias after use
  unsigned short* agg1 = (unsigned short*)alloc((size_t)NN * 96 * 2);
  unsigned short* xb   = (unsigned short*)alloc((size_t)NN * 64 * 2);
  unsigned short* W1b  = (unsigned short*)alloc(12288 * 2);
  unsigned short* Wl2b = (unsigned short*)alloc(16384 * 2);
  unsigned short* Wr2b = (unsigned short*)alloc(16384 * 2);
  unsigned short* Wl3b = (unsigned short*)alloc(16384 * 2);
  unsigned short* Wr3b = (unsigned short*)alloc(16384 * 2);
  unsigned short* W4b  = (unsigned short*)alloc(12288 * 2);

  // aliases inside the BIG recEA buffer (56.4 MB >= 4 x 12.8 MB), valid after k_aggEA
  unsigned short* h1   = (unsigned short*)recEA;
  unsigned short* aggH = h1 + (size_t)NN * 128;
  unsigned short* h2   = h1 + (size_t)2 * NN * 128;
  unsigned short* h3   = h1 + (size_t)3 * NN * 128;

  int* rb0 = rowbeg3;            int* dg0 = deg3;
  int* rb1 = rowbeg3 + NN;       int* dg1 = deg3 + NN;
  int* rb2 = rowbeg3 + 2 * NN;   int* dg2 = deg3 + 2 * NN;

  const int gPP   = (NE + PTP - 1) / PTP;      // 1563
  const int gP2   = (NE + PT2 - 1) / PT2;      // 391
  const int gAgg  = (NN * 64) / 256;           // 12500
  const int gTile = (3125 * 8 * 64) / 256;     // 6250
  const int gRead = (3125 * 64 + 255) / 256;   // 782
  const int gCvt  = (CVT_END + 255) / 256;

  k_cvt_all<<<gCvt, 256, 0, stream>>>(x, W1, Wl2, Wr2, Wl3, Wr3, W4,
                                      xb, W1b, Wl2b, Wr2b, Wl3b, Wr3b, W4b, gcur);

  // ---- layer 1 (conv1): payload partition + bucket ea-agg + x-gather ----
  k_partP<<<gPP, 256, 0, stream>>>(ei0, ea, gcur, recDS, recEA);
  k_build<<<KB, 256, 0, stream>>>(recDS, gcur, adjI, rb0, dg0);
  k_aggEA<<<KB, 256, 0, stream>>>(recDS, recEA, gcur, agg1);
  k_aggX<<<gAgg, 256, 0, stream>>>(rb0, dg0, adjI, xb, agg1);
  k_lin1<<<gTile, 256, 0, stream>>>(agg1, W1b, b1, g1, be1, m1, v1, dg0, h1);

  // ---- layer 2 (SAGE) ----
  k_part<<<gP2, 256, 0, stream>>>(ei1, gcur + KB, recDS);
  k_build<<<KB, 256, 0, stream>>>(recDS, gcur + KB, adjI, rb1, dg1);
  k_aggH<<<gAgg, 256, 0, stream>>>(rb1, dg1, adjI, h1, aggH);
  k_sage<<<gTile, 256, 0, stream>>>(aggH, h1, Wl2b, bl2, Wr2b, g2, be2, m2, v2, h2);

  // ---- layer 3 (SAGE) ----
  k_part<<<gP2, 256, 0, stream>>>(ei2, gcur + 2 * KB, recDS);
  k_build<<<KB, 256, 0, stream>>>(recDS, gcur + 2 * KB, adjI, rb2, dg2);
  k_aggH<<<gAgg, 256, 0, stream>>>(rb2, dg2, adjI, h2, aggH);
  k_sage<<<gTile, 256, 0, stream>>>(aggH, h2, Wl3b, bl3, Wr3b, g3, be3, m3, v3, h3);

  // ---- readout ----
  k_readout<<<gRead, 256, 0, stream>>>(h3, xb, W4b, b4, W5, b5, (float*)d_out);

  (void)in_sizes; (void)n_in; (void)out_size; (void)ws_size;
}

// Round 6
// 567.709 us; speedup vs baseline: 1.2740x; 1.2740x over previous
//
#include <hip/hip_runtime.h>
#include <hip/hip_bf16.h>
#include <stdint.h>

#define NN 50000
#define NE 800000
#define EPS 1e-5f

// CSR bucket params
#define KB 196       // buckets = ceil(NN / NPB)
#define SH 8         // bucket = dst >> SH
#define NPB 256      // nodes per bucket
#define RCAP 4500    // slots per bucket (mean 4082, +6.6 sigma)
#define PTP 512      // edges per payload-partition block
#define PT2 2048     // edges per DS-partition block

typedef __attribute__((ext_vector_type(8))) short bf16x8;
typedef __attribute__((ext_vector_type(4))) float floatx4;

static __device__ __forceinline__ float bf2f(unsigned int u){
  union { unsigned int i; float f; } c; c.i = u << 16; return c.f;
}
static __device__ __forceinline__ unsigned short f2bf(float f){
  union { float f; unsigned int i; } c; c.f = f;
  unsigned int x = c.i;
  return (unsigned short)((x + 0x7fffu + ((x >> 16) & 1u)) >> 16);
}

// fused f32 -> bf16 converter for x + the 6 GEMM weight matrices; also zeros bucket cursors
#define CVT_X   3200000
#define CVT_W1  3212288
#define CVT_WL2 3228672
#define CVT_WR2 3245056
#define CVT_WL3 3261440
#define CVT_WR3 3277824
#define CVT_END 3290112
__global__ void k_cvt_all(const float* __restrict__ x,  const float* __restrict__ W1,
                          const float* __restrict__ Wl2, const float* __restrict__ Wr2,
                          const float* __restrict__ Wl3, const float* __restrict__ Wr3,
                          const float* __restrict__ W4,
                          unsigned short* __restrict__ xb,  unsigned short* __restrict__ W1b,
                          unsigned short* __restrict__ Wl2b, unsigned short* __restrict__ Wr2b,
                          unsigned short* __restrict__ Wl3b, unsigned short* __restrict__ Wr3b,
                          unsigned short* __restrict__ W4b, int* __restrict__ gcur){
  int i = blockIdx.x * 256 + threadIdx.x;
  if(i >= CVT_END) return;
  if(i < 3 * KB) gcur[i] = 0;
  if(i < CVT_X)        xb[i] = f2bf(x[i]);
  else if(i < CVT_W1)  W1b[i - CVT_X]    = f2bf(W1[i - CVT_X]);
  else if(i < CVT_WL2) Wl2b[i - CVT_W1]  = f2bf(Wl2[i - CVT_W1]);
  else if(i < CVT_WR2) Wr2b[i - CVT_WL2] = f2bf(Wr2[i - CVT_WL2]);
  else if(i < CVT_WL3) Wl3b[i - CVT_WR2] = f2bf(Wl3[i - CVT_WR2]);
  else if(i < CVT_WR3) Wr3b[i - CVT_WL3] = f2bf(Wr3[i - CVT_WL3]);
  else                 W4b[i - CVT_WR3]  = f2bf(W4[i - CVT_WR3]);
}

// ---- layer-0 partition WITH ea payload: streams ei + ea sequentially,
// writes bucket-grouped recDS {dst,src} and recEA (32 bf16 = 64B rows) ----
__global__ void k_partP(const int* __restrict__ ei, const float* __restrict__ ea,
                        int* __restrict__ gcur,
                        int2* __restrict__ recDS, unsigned int* __restrict__ recEA){
  __shared__ int2 stage[PTP];
  __shared__ int slotArr[PTP];
  __shared__ unsigned int pay[PTP * 16];
  __shared__ int hist[KB], ex[KB], cur[KB], gbase[KB];
  __shared__ int tot;
  int tid = threadIdx.x;
  int tile = blockIdx.x * PTP;
  int cnt_local = NE - tile; if(cnt_local > PTP) cnt_local = PTP;
  for(int i = tid; i < KB; i += 256) hist[i] = 0;
  __syncthreads();
  int dst[2], src[2];
  #pragma unroll
  for(int j = 0; j < 2; j++){
    int t = j * 256 + tid;
    if(t < cnt_local){ src[j] = ei[tile + t]; dst[j] = ei[NE + tile + t]; atomicAdd(&hist[dst[j] >> SH], 1); }
    else dst[j] = -1;
  }
  __syncthreads();
  if(tid == 0){ int run = 0; for(int b = 0; b < KB; b++){ ex[b] = run; cur[b] = run; run += hist[b]; } tot = run; }
  if(tid < KB) gbase[tid] = atomicAdd(&gcur[tid], hist[tid]);
  __syncthreads();
  #pragma unroll
  for(int j = 0; j < 2; j++){
    if(dst[j] >= 0){
      int b = dst[j] >> SH;
      int s = atomicAdd(&cur[b], 1);
      stage[s] = make_int2(dst[j], src[j]);
      slotArr[j * 256 + tid] = s;
    }
  }
  __syncthreads();
  // payload: sequential coalesced ea read, scatter into LDS by slot (16 lanes per edge)
  {
    int g = tid >> 4, li = tid & 15;
    for(int t = g; t < cnt_local; t += 16){
      int s = slotArr[t];
      float2 v = *(const float2*)(ea + (size_t)(tile + t) * 32 + li * 2);
      pay[s * 16 + li] = (unsigned int)f2bf(v.x) | ((unsigned int)f2bf(v.y) << 16);
    }
  }
  __syncthreads();
  // flush DS recs (bucket-run grouped)
  for(int s = tid; s < tot; s += 256){
    int2 r = stage[s];
    int b = r.x >> SH;
    recDS[b * RCAP + gbase[b] + (s - ex[b])] = r;
  }
  // flush payload rows (4 lanes x 16B per row, rows in s-order => bucket-run contiguous)
  {
    int g4 = tid >> 2, l4 = tid & 3;
    for(int s = g4; s < tot; s += 64){
      int b = stage[s].x >> SH;
      int dslot = b * RCAP + gbase[b] + (s - ex[b]);
      uint4 v = *(uint4*)&pay[s * 16 + l4 * 4];
      *((uint4*)(recEA + (size_t)dslot * 16) + l4) = v;
    }
  }
}

// ---- DS-only partition for layers 1/2 ----
__global__ void k_part(const int* __restrict__ ei, int* __restrict__ gcur, int2* __restrict__ rec){
  __shared__ int2 stage[PT2];
  __shared__ int hist[KB], ex[KB], cur[KB], gbase[KB];
  __shared__ int tot;
  int tid = threadIdx.x;
  int tile = blockIdx.x * PT2;
  for(int i = tid; i < KB; i += 256) hist[i] = 0;
  __syncthreads();
  int dst[8], src[8];
  #pragma unroll
  for(int j = 0; j < 8; j++){
    int e = tile + j * 256 + tid;
    if(e < NE){ src[j] = ei[e]; dst[j] = ei[NE + e]; atomicAdd(&hist[dst[j] >> SH], 1); }
    else dst[j] = -1;
  }
  __syncthreads();
  if(tid == 0){ int run = 0; for(int b = 0; b < KB; b++){ ex[b] = run; cur[b] = run; run += hist[b]; } tot = run; }
  if(tid < KB) gbase[tid] = atomicAdd(&gcur[tid], hist[tid]);
  __syncthreads();
  #pragma unroll
  for(int j = 0; j < 8; j++){
    if(dst[j] >= 0){
      int b = dst[j] >> SH;
      int s = atomicAdd(&cur[b], 1);
      stage[s] = make_int2(dst[j], src[j]);
    }
  }
  __syncthreads();
  for(int s = tid; s < tot; s += 256){
    int2 r = stage[s];
    int b = r.x >> SH;
    rec[b * RCAP + gbase[b] + (s - ex[b])] = r;
  }
}

// ---- per-bucket CSR build for L0: adj2[p] = {src, absolute payload slot} ----
__global__ void k_build0(const int2* __restrict__ rec, const int* __restrict__ gcnt,
                         int2* __restrict__ adj2, int* __restrict__ rowbeg, int* __restrict__ deg){
  __shared__ int cnt[NPB], cur2[NPB];
  __shared__ int part[256];
  int b = blockIdx.x, tid = threadIdx.x;
  int n0 = b << SH;
  int nr = gcnt[b];
  const int2* r = rec + b * RCAP;
  cnt[tid] = 0;
  __syncthreads();
  for(int k = tid; k < nr; k += 256) atomicAdd(&cnt[r[k].x - n0], 1);
  __syncthreads();
  int c0 = cnt[tid];
  part[tid] = c0;
  __syncthreads();
  for(int d = 1; d < 256; d <<= 1){
    int v = (tid >= d) ? part[tid - d] : 0;
    __syncthreads();
    part[tid] += v;
    __syncthreads();
  }
  int base = part[tid] - c0;
  cur2[tid] = base;
  __syncthreads();
  int n = n0 + tid;
  if(n < NN){ rowbeg[n] = b * RCAP + base; deg[n] = c0; }
  for(int k = tid; k < nr; k += 256){
    int2 q = r[k];
    int p = atomicAdd(&cur2[q.x - n0], 1);
    adj2[b * RCAP + p] = make_int2(q.y, b * RCAP + k);
  }
}

// ---- per-bucket CSR build (L1/L2): int adj ----
__global__ void k_build(const int2* __restrict__ rec, const int* __restrict__ gcnt,
                        int* __restrict__ adj, int* __restrict__ rowbeg, int* __restrict__ deg){
  __shared__ int cnt[NPB], cur2[NPB];
  __shared__ int part[256];
  int b = blockIdx.x, tid = threadIdx.x;
  int n0 = b << SH;
  int nr = gcnt[b];
  const int2* r = rec + b * RCAP;
  cnt[tid] = 0;
  __syncthreads();
  for(int k = tid; k < nr; k += 256) atomicAdd(&cnt[r[k].x - n0], 1);
  __syncthreads();
  int c0 = cnt[tid];
  part[tid] = c0;
  __syncthreads();
  for(int d = 1; d < 256; d <<= 1){
    int v = (tid >= d) ? part[tid - d] : 0;
    __syncthreads();
    part[tid] += v;
    __syncthreads();
  }
  int base = part[tid] - c0;
  cur2[tid] = base;
  __syncthreads();
  int n = n0 + tid;
  if(n < NN){ rowbeg[n] = b * RCAP + base; deg[n] = c0; }
  for(int k = tid; k < nr; k += 256){
    int2 q = r[k];
    int p = atomicAdd(&cur2[q.x - n0], 1);
    adj[b * RCAP + p] = q.y;
  }
}

// ---- fused L0 aggregation: wave per node; 16 lanes/edge, 4 edges/iter x 2 unroll.
// Per edge: lanes 0-7 gather xb row (16B each), lanes 8-15 gather payload row (8B each).
__global__ void k_aggXE(const int* __restrict__ rowbeg, const int* __restrict__ deg,
                        const int2* __restrict__ adj2,
                        const unsigned short* __restrict__ xb, const unsigned int* __restrict__ recEA,
                        unsigned short* __restrict__ agg){
  int w = (blockIdx.x * blockDim.x + threadIdx.x) >> 6;
  int lane = threadIdx.x & 63;
  if(w >= NN) return;
  int sub = lane >> 4, li = lane & 15;
  int r0 = rowbeg[w], dg = deg[w], r1 = r0 + dg;
  float acc[8] = {0.f,0.f,0.f,0.f,0.f,0.f,0.f,0.f};
  for(int k = r0; k < r1; k += 8){
    int e0 = k + sub, e1 = k + 4 + sub;
    int i0 = e0 < r1 ? e0 : r1 - 1;
    int i1 = e1 < r1 ? e1 : r1 - 1;
    float m0 = e0 < r1 ? 1.f : 0.f;
    float m1 = e1 < r1 ? 1.f : 0.f;
    int2 a0 = adj2[i0], a1 = adj2[i1];
    if(li < 8){
      uint4 v0 = *(const uint4*)(xb + (size_t)a0.x * 64 + li * 8);
      uint4 v1 = *(const uint4*)(xb + (size_t)a1.x * 64 + li * 8);
      acc[0] += m0 * bf2f(v0.x & 0xffffu); acc[1] += m0 * bf2f(v0.x >> 16);
      acc[2] += m0 * bf2f(v0.y & 0xffffu); acc[3] += m0 * bf2f(v0.y >> 16);
      acc[4] += m0 * bf2f(v0.z & 0xffffu); acc[5] += m0 * bf2f(v0.z >> 16);
      acc[6] += m0 * bf2f(v0.w & 0xffffu); acc[7] += m0 * bf2f(v0.w >> 16);
      acc[0] += m1 * bf2f(v1.x & 0xffffu); acc[1] += m1 * bf2f(v1.x >> 16);
      acc[2] += m1 * bf2f(v1.y & 0xffffu); acc[3] += m1 * bf2f(v1.y >> 16);
      acc[4] += m1 * bf2f(v1.z & 0xffffu); acc[5] += m1 * bf2f(v1.z >> 16);
      acc[6] += m1 * bf2f(v1.w & 0xffffu); acc[7] += m1 * bf2f(v1.w >> 16);
    } else {
      int j = li - 8;
      uint2 p0 = *(const uint2*)(recEA + (size_t)a0.y * 16 + j * 2);
      uint2 p1 = *(const uint2*)(recEA + (size_t)a1.y * 16 + j * 2);
      acc[0] += m0 * bf2f(p0.x & 0xffffu); acc[1] += m0 * bf2f(p0.x >> 16);
      acc[2] += m0 * bf2f(p0.y & 0xffffu); acc[3] += m0 * bf2f(p0.y >> 16);
      acc[0] += m1 * bf2f(p1.x & 0xffffu); acc[1] += m1 * bf2f(p1.x >> 16);
      acc[2] += m1 * bf2f(p1.y & 0xffffu); acc[3] += m1 * bf2f(p1.y >> 16);
    }
  }
  #pragma unroll
  for(int d = 16; d < 64; d <<= 1){
    #pragma unroll
    for(int i = 0; i < 8; i++) acc[i] += __shfl_xor(acc[i], d, 64);
  }
  if(sub == 0){
    float inv = 1.0f / (float)(dg > 0 ? dg : 1);
    if(li < 8){
      unsigned int q0 = (unsigned int)f2bf(acc[0]*inv) | ((unsigned int)f2bf(acc[1]*inv) << 16);
      unsigned int q1 = (unsigned int)f2bf(acc[2]*inv) | ((unsigned int)f2bf(acc[3]*inv) << 16);
      unsigned int q2 = (unsigned int)f2bf(acc[4]*inv) | ((unsigned int)f2bf(acc[5]*inv) << 16);
      unsigned int q3 = (unsigned int)f2bf(acc[6]*inv) | ((unsigned int)f2bf(acc[7]*inv) << 16);
      *(uint4*)(agg + (size_t)w * 96 + li * 8) = make_uint4(q0, q1, q2, q3);
    } else {
      int j = li - 8;
      unsigned int q0 = (unsigned int)f2bf(acc[0]*inv) | ((unsigned int)f2bf(acc[1]*inv) << 16);
      unsigned int q1 = (unsigned int)f2bf(acc[2]*inv) | ((unsigned int)f2bf(acc[3]*inv) << 16);
      *(uint2*)(agg + (size_t)w * 96 + 64 + j * 4) = make_uint2(q0, q1);
    }
  }
}

// ---- h aggregation: wave per node; 16 lanes/edge x 4 edges/iter x 2 unroll ----
__global__ void k_aggH(const int* __restrict__ rowbeg, const int* __restrict__ deg,
                       const int* __restrict__ adj,
                       const unsigned short* __restrict__ h, unsigned short* __restrict__ agg){
  int w = (blockIdx.x * blockDim.x + threadIdx.x) >> 6;
  int lane = threadIdx.x & 63;
  if(w >= NN) return;
  int sub = lane >> 4, li = lane & 15;
  int r0 = rowbeg[w], dg = deg[w], r1 = r0 + dg;
  float acc[8] = {0.f,0.f,0.f,0.f,0.f,0.f,0.f,0.f};
  for(int k = r0; k < r1; k += 8){
    int e0 = k + sub, e1 = k + 4 + sub;
    int i0 = e0 < r1 ? e0 : r1 - 1;
    int i1 = e1 < r1 ? e1 : r1 - 1;
    float m0 = e0 < r1 ? 1.f : 0.f;
    float m1 = e1 < r1 ? 1.f : 0.f;
    int s0 = adj[i0], s1 = adj[i1];
    uint4 v0 = *(const uint4*)(h + (size_t)s0 * 128 + li * 8);
    uint4 v1 = *(const uint4*)(h + (size_t)s1 * 128 + li * 8);
    acc[0] += m0 * bf2f(v0.x & 0xffffu); acc[1] += m0 * bf2f(v0.x >> 16);
    acc[2] += m0 * bf2f(v0.y & 0xffffu); acc[3] += m0 * bf2f(v0.y >> 16);
    acc[4] += m0 * bf2f(v0.z & 0xffffu); acc[5] += m0 * bf2f(v0.z >> 16);
    acc[6] += m0 * bf2f(v0.w & 0xffffu); acc[7] += m0 * bf2f(v0.w >> 16);
    acc[0] += m1 * bf2f(v1.x & 0xffffu); acc[1] += m1 * bf2f(v1.x >> 16);
    acc[2] += m1 * bf2f(v1.y & 0xffffu); acc[3] += m1 * bf2f(v1.y >> 16);
    acc[4] += m1 * bf2f(v1.z & 0xffffu); acc[5] += m1 * bf2f(v1.z >> 16);
    acc[6] += m1 * bf2f(v1.w & 0xffffu); acc[7] += m1 * bf2f(v1.w >> 16);
  }
  #pragma unroll
  for(int d = 16; d < 64; d <<= 1){
    #pragma unroll
    for(int i = 0; i < 8; i++) acc[i] += __shfl_xor(acc[i], d, 64);
  }
  if(sub == 0){
    float inv = 1.0f / (float)(dg > 0 ? dg : 1);
    unsigned int p0 = (unsigned int)f2bf(acc[0]*inv) | ((unsigned int)f2bf(acc[1]*inv) << 16);
    unsigned int p1 = (unsigned int)f2bf(acc[2]*inv) | ((unsigned int)f2bf(acc[3]*inv) << 16);
    unsigned int p2 = (unsigned int)f2bf(acc[4]*inv) | ((unsigned int)f2bf(acc[5]*inv) << 16);
    unsigned int p3 = (unsigned int)f2bf(acc[6]*inv) | ((unsigned int)f2bf(acc[7]*inv) << 16);
    *(uint4*)(agg + (size_t)w * 128 + li * 8) = make_uint4(p0, p1, p2, p3);
  }
}

// conv1 dense part: h1 = relu(bn(relu(mask_deg(agg @ W1^T + b1))))
__global__ void k_lin1(const unsigned short* __restrict__ agg, const unsigned short* __restrict__ W1,
                       const float* __restrict__ b1,
                       const float* __restrict__ g1, const float* __restrict__ be1,
                       const float* __restrict__ m1, const float* __restrict__ v1,
                       const int* __restrict__ deg, unsigned short* __restrict__ h1){
  int wave = (blockIdx.x * blockDim.x + threadIdx.x) >> 6;
  int lane = threadIdx.x & 63;
  int mt = wave >> 3, nt = wave & 7;
  if(mt >= 3125) return;
  int node0 = mt * 16;
  int col = lane & 15, quad = lane >> 4;
  int o = nt * 16 + col;
  int arow = node0 + col;
  floatx4 acc = {0.f, 0.f, 0.f, 0.f};
  #pragma unroll
  for(int kc = 0; kc < 3; kc++){
    bf16x8 a = *(const bf16x8*)(agg + arow * 96 + kc * 32 + quad * 8);
    bf16x8 b = *(const bf16x8*)(W1 + o * 96 + kc * 32 + quad * 8);
    acc = __builtin_amdgcn_mfma_f32_16x16x32_bf16(a, b, acc, 0, 0, 0);
  }
  float bb = b1[o];
  float sc = g1[o] * rsqrtf(v1[o] + EPS);
  float mv = m1[o], bev = be1[o];
  #pragma unroll
  for(int r = 0; r < 4; r++){
    int node = node0 + quad * 4 + r;
    float pre = (deg[node] > 0) ? (acc[r] + bb) : 0.0f;   // ref: empty segment -> mean 0, bias never added
    float t = fmaxf(pre, 0.f);
    float bn = sc * (t - mv) + bev;
    h1[node * 128 + o] = f2bf(fmaxf(bn, 0.f));
  }
}

// SAGE: hout = relu(bn(agg @ Wl^T + bl + hin @ Wr^T))
__global__ void k_sage(const unsigned short* __restrict__ agg, const unsigned short* __restrict__ hin,
                       const unsigned short* __restrict__ Wl, const float* __restrict__ bl,
                       const unsigned short* __restrict__ Wr,
                       const float* __restrict__ g, const float* __restrict__ be,
                       const float* __restrict__ m, const float* __restrict__ v,
                       unsigned short* __restrict__ hout){
  int wave = (blockIdx.x * blockDim.x + threadIdx.x) >> 6;
  int lane = threadIdx.x & 63;
  int mt = wave >> 3, nt = wave & 7;
  if(mt >= 3125) return;
  int node0 = mt * 16;
  int col = lane & 15, quad = lane >> 4;
  int o = nt * 16 + col;
  int arow = node0 + col;
  floatx4 acc = {0.f, 0.f, 0.f, 0.f};
  #pragma unroll
  for(int kc = 0; kc < 4; kc++){
    bf16x8 a = *(const bf16x8*)(agg + arow * 128 + kc * 32 + quad * 8);
    bf16x8 b = *(const bf16x8*)(Wl + o * 128 + kc * 32 + quad * 8);
    acc = __builtin_amdgcn_mfma_f32_16x16x32_bf16(a, b, acc, 0, 0, 0);
  }
  #pragma unroll
  for(int kc = 0; kc < 4; kc++){
    bf16x8 a = *(const bf16x8*)(hin + arow * 128 + kc * 32 + quad * 8);
    bf16x8 b = *(const bf16x8*)(Wr + o * 128 + kc * 32 + quad * 8);
    acc = __builtin_amdgcn_mfma_f32_16x16x32_bf16(a, b, acc, 0, 0, 0);
  }
  float blv = bl[o];
  float sc = g[o] * rsqrtf(v[o] + EPS);
  float mv = m[o], bev = be[o];
  #pragma unroll
  for(int r = 0; r < 4; r++){
    int node = node0 + quad * 4 + r;
    float pre = acc[r] + blv;
    float bn = sc * (pre - mv) + bev;
    hout[node * 128 + o] = f2bf(fmaxf(bn, 0.f));
  }
}

// readout: z = relu([h3 | x] @ W4^T + b4) (64), out = z @ W5^T + b5  (f32 out)
__global__ void k_readout(const unsigned short* __restrict__ h3, const unsigned short* __restrict__ xb,
                          const unsigned short* __restrict__ W4, const float* __restrict__ b4,
                          const float* __restrict__ W5, const float* __restrict__ b5,
                          float* __restrict__ out){
  int wave = (blockIdx.x * blockDim.x + threadIdx.x) >> 6;
  int lane = threadIdx.x & 63;
  if(wave >= 3125) return;
  int node0 = wave * 16;
  int col = lane & 15, quad = lane >> 4;
  int arow = node0 + col;
  float partial[4] = {0.f, 0.f, 0.f, 0.f};
  #pragma unroll
  for(int nt = 0; nt < 4; nt++){
    int o = nt * 16 + col;
    floatx4 acc = {0.f, 0.f, 0.f, 0.f};
    #pragma unroll
    for(int kc = 0; kc < 4; kc++){
      bf16x8 a = *(const bf16x8*)(h3 + arow * 128 + kc * 32 + quad * 8);
      bf16x8 b = *(const bf16x8*)(W4 + o * 192 + kc * 32 + quad * 8);
      acc = __builtin_amdgcn_mfma_f32_16x16x32_bf16(a, b, acc, 0, 0, 0);
    }
    #pragma unroll
    for(int kc = 0; kc < 2; kc++){
      bf16x8 a = *(const bf16x8*)(xb + arow * 64 + kc * 32 + quad * 8);
      bf16x8 b = *(const bf16x8*)(W4 + o * 192 + 128 + kc * 32 + quad * 8);
      acc = __builtin_amdgcn_mfma_f32_16x16x32_bf16(a, b, acc, 0, 0, 0);
    }
    float bb = b4[o];
    float w5 = W5[o];
    #pragma unroll
    for(int r = 0; r < 4; r++)
      partial[r] += fmaxf(acc[r] + bb, 0.f) * w5;
  }
  #pragma unroll
  for(int d = 1; d < 16; d <<= 1){
    #pragma unroll
    for(int r = 0; r < 4; r++)
      partial[r] += __shfl_xor(partial[r], d, 64);
  }
  if(col == 0){
    float b5f = b5[0];
    #pragma unroll
    for(int r = 0; r < 4; r++)
      out[node0 + quad * 4 + r] = partial[r] + b5f;
  }
}

extern "C" void kernel_launch(void* const* d_in, const int* in_sizes, int n_in,
                              void* d_out, int out_size, void* d_ws, size_t ws_size,
                              hipStream_t stream) {
  const float* x   = (const float*)d_in[0];
  const int* ei0   = (const int*)d_in[1];
  const int* ei1   = (const int*)d_in[2];
  const int* ei2   = (const int*)d_in[3];
  const float* ea  = (const float*)d_in[4];
  const float* W1  = (const float*)d_in[5];
  const float* b1  = (const float*)d_in[6];
  const float* g1  = (const float*)d_in[7];
  const float* be1 = (const float*)d_in[8];
  const float* m1  = (const float*)d_in[9];
  const float* v1  = (const float*)d_in[10];
  const float* Wl2 = (const float*)d_in[11];
  const float* bl2 = (const float*)d_in[12];
  const float* Wr2 = (const float*)d_in[13];
  const float* g2  = (const float*)d_in[14];
  const float* be2 = (const float*)d_in[15];
  const float* m2  = (const float*)d_in[16];
  const float* v2  = (const float*)d_in[17];
  const float* Wl3 = (const float*)d_in[18];
  const float* bl3 = (const float*)d_in[19];
  const float* Wr3 = (const float*)d_in[20];
  const float* g3  = (const float*)d_in[21];
  const float* be3 = (const float*)d_in[22];
  const float* m3  = (const float*)d_in[23];
  const float* v3  = (const float*)d_in[24];
  const float* W4  = (const float*)d_in[25];
  const float* b4  = (const float*)d_in[26];
  const float* W5  = (const float*)d_in[27];
  const float* b5  = (const float*)d_in[28];

  char* ws = (char*)d_ws;
  size_t off = 0;
  auto alloc = [&](size_t bytes) -> void* {
    void* p = (void*)(ws + off);
    off += (bytes + 255) & ~(size_t)255;
    return p;
  };
  int* gcur    = (int*)alloc(3 * KB * sizeof(int));
  int* rowbeg3 = (int*)alloc(3 * NN * sizeof(int));
  int* deg3    = (int*)alloc(3 * NN * sizeof(int));
  int2* recDS  = (int2*)alloc((size_t)KB * RCAP * 8);
  int2* adj2   = (int2*)alloc((size_t)KB * RCAP * 8);     // L0: int2 {src,slot}; L1/L2: int adj (aliased)
  unsigned int* recEA = (unsigned int*)alloc((size_t)KB * RCAP * 64);  // BIG: h1/aggH/h2/h3 alias after use
  unsigned short* agg1 = (unsigned short*)alloc((size_t)NN * 96 * 2);
  unsigned short* xb   = (unsigned short*)alloc((size_t)NN * 64 * 2);
  unsigned short* W1b  = (unsigned short*)alloc(12288 * 2);
  unsigned short* Wl2b = (unsigned short*)alloc(16384 * 2);
  unsigned short* Wr2b = (unsigned short*)alloc(16384 * 2);
  unsigned short* Wl3b = (unsigned short*)alloc(16384 * 2);
  unsigned short* Wr3b = (unsigned short*)alloc(16384 * 2);
  unsigned short* W4b  = (unsigned short*)alloc(12288 * 2);

  int* adjI = (int*)adj2;

  // aliases inside the BIG recEA buffer (56.4 MB >= 4 x 12.8 MB), valid after k_aggXE consumed recEA
  unsigned short* h1   = (unsigned short*)recEA;
  unsigned short* aggH = h1 + (size_t)NN * 128;
  unsigned short* h2   = h1 + (size_t)2 * NN * 128;
  unsigned short* h3   = h1 + (size_t)3 * NN * 128;

  int* rb0 = rowbeg3;            int* dg0 = deg3;
  int* rb1 = rowbeg3 + NN;       int* dg1 = deg3 + NN;
  int* rb2 = rowbeg3 + 2 * NN;   int* dg2 = deg3 + 2 * NN;

  const int gPP   = (NE + PTP - 1) / PTP;      // 1563
  const int gP2   = (NE + PT2 - 1) / PT2;      // 391
  const int gAgg  = (NN * 64) / 256;           // 12500
  const int gTile = (3125 * 8 * 64) / 256;     // 6250
  const int gRead = (3125 * 64 + 255) / 256;   // 782
  const int gCvt  = (CVT_END + 255) / 256;

  k_cvt_all<<<gCvt, 256, 0, stream>>>(x, W1, Wl2, Wr2, Wl3, Wr3, W4,
                                      xb, W1b, Wl2b, Wr2b, Wl3b, Wr3b, W4b, gcur);

  // ---- layer 1 (conv1): payload partition + fused x/ea gather ----
  k_partP<<<gPP, 256, 0, stream>>>(ei0, ea, gcur, recDS, recEA);
  k_build0<<<KB, 256, 0, stream>>>(recDS, gcur, adj2, rb0, dg0);
  k_aggXE<<<gAgg, 256, 0, stream>>>(rb0, dg0, adj2, xb, recEA, agg1);
  k_lin1<<<gTile, 256, 0, stream>>>(agg1, W1b, b1, g1, be1, m1, v1, dg0, h1);

  // ---- layer 2 (SAGE) ----
  k_part<<<gP2, 256, 0, stream>>>(ei1, gcur + KB, recDS);
  k_build<<<KB, 256, 0, stream>>>(recDS, gcur + KB, adjI, rb1, dg1);
  k_aggH<<<gAgg, 256, 0, stream>>>(rb1, dg1, adjI, h1, aggH);
  k_sage<<<gTile, 256, 0, stream>>>(aggH, h1, Wl2b, bl2, Wr2b, g2, be2, m2, v2, h2);

  // ---- layer 3 (SAGE) ----
  k_part<<<gP2, 256, 0, stream>>>(ei2, gcur + 2 * KB, recDS);
  k_build<<<KB, 256, 0, stream>>>(recDS, gcur + 2 * KB, adjI, rb2, dg2);
  k_aggH<<<gAgg, 256, 0, stream>>>(rb2, dg2, adjI, h2, aggH);
  k_sage<<<gTile, 256, 0, stream>>>(aggH, h2, Wl3b, bl3, Wr3b, g3, be3, m3, v3, h3);

  // ---- readout ----
  k_readout<<<gRead, 256, 0, stream>>>(h3, xb, W4b, b4, W5, b5, (float*)d_out);

  (void)in_sizes; (void)n_in; (void)out_size; (void)ws_size;
}